// Round 1
// baseline (1623.956 us; speedup 1.0000x reference)
//
#include <hip/hip_runtime.h>

#define N_NODES 50000
#define T_STEPS 8
#define C_FEAT  64
#define E_EDGES 800000
#define K_DIM   512   // T*C

// ---------------- zero workspace ----------------
__global__ __launch_bounds__(256) void zero_f4(float* __restrict__ p, int n_f4) {
    int i = blockIdx.x * 256 + threadIdx.x;
    if (i < n_f4) ((float4*)p)[i] = make_float4(0.f, 0.f, 0.f, 0.f);
}

// ---------------- scatter-add: 16 threads per edge, float4 each ----------------
// cat layout: [N, T*C], cat[dst][t*64 + c]
__global__ __launch_bounds__(256) void scatter_add(const float* __restrict__ x,
                                                   const int* __restrict__ src,
                                                   const int* __restrict__ dst,
                                                   const int* __restrict__ tix,
                                                   float* __restrict__ cat) {
    int g = blockIdx.x * 256 + threadIdx.x;
    int e = g >> 4;
    int q = g & 15;
    if (e >= E_EDGES) return;
    int s = src[e], d = dst[e], t = tix[e];
    float4 v = ((const float4*)(x + (size_t)s * C_FEAT))[q];
    float* o = cat + (size_t)d * K_DIM + t * C_FEAT + q * 4;
    atomicAdd(o + 0, v.x);
    atomicAdd(o + 1, v.y);
    atomicAdd(o + 2, v.z);
    atomicAdd(o + 3, v.w);
}

// ---------------- GEMM: [N,512] @ [512,64] + bias, relu -> [N,64] ----------------
// 64 nodes x 64 outputs per block, 256 threads, 4x4 micro-tile per thread.
__global__ __launch_bounds__(256) void gemm_tlin(const float* __restrict__ A,
                                                 const float* __restrict__ W,
                                                 const float* __restrict__ bias,
                                                 float* __restrict__ out) {
    __shared__ float sA[64][68];   // +4 pad: bank-spread, float4-aligned rows
    __shared__ float sW[64][68];
    const int nbase = blockIdx.x * 64;
    const int tid = threadIdx.x;
    const int j0 = (tid & 15) * 4;
    const int n0 = (tid >> 4) * 4;
    float acc[4][4] = {};

    for (int t = 0; t < T_STEPS; ++t) {
        // stage A chunk [64 nodes x 64 k] and W chunk [64 k x 64 j]
        #pragma unroll
        for (int i = 0; i < 4; ++i) {
            int row  = (tid >> 4) + i * 16;   // 0..63
            int col4 = (tid & 15);            // float4 col
            int node = nbase + row;
            float4 v = make_float4(0.f, 0.f, 0.f, 0.f);
            if (node < N_NODES)
                v = *(const float4*)(A + (size_t)node * K_DIM + t * 64 + col4 * 4);
            *(float4*)&sA[row][col4 * 4] = v;
            *(float4*)&sW[row][col4 * 4] =
                *(const float4*)(W + (size_t)(t * 64 + row) * C_FEAT + col4 * 4);
        }
        __syncthreads();
        #pragma unroll 8
        for (int k = 0; k < 64; ++k) {
            float4 w = *(float4*)&sW[k][j0];
            float a0 = sA[n0 + 0][k];
            float a1 = sA[n0 + 1][k];
            float a2 = sA[n0 + 2][k];
            float a3 = sA[n0 + 3][k];
            acc[0][0] = fmaf(a0, w.x, acc[0][0]); acc[0][1] = fmaf(a0, w.y, acc[0][1]);
            acc[0][2] = fmaf(a0, w.z, acc[0][2]); acc[0][3] = fmaf(a0, w.w, acc[0][3]);
            acc[1][0] = fmaf(a1, w.x, acc[1][0]); acc[1][1] = fmaf(a1, w.y, acc[1][1]);
            acc[1][2] = fmaf(a1, w.z, acc[1][2]); acc[1][3] = fmaf(a1, w.w, acc[1][3]);
            acc[2][0] = fmaf(a2, w.x, acc[2][0]); acc[2][1] = fmaf(a2, w.y, acc[2][1]);
            acc[2][2] = fmaf(a2, w.z, acc[2][2]); acc[2][3] = fmaf(a2, w.w, acc[2][3]);
            acc[3][0] = fmaf(a3, w.x, acc[3][0]); acc[3][1] = fmaf(a3, w.y, acc[3][1]);
            acc[3][2] = fmaf(a3, w.z, acc[3][2]); acc[3][3] = fmaf(a3, w.w, acc[3][3]);
        }
        __syncthreads();
    }

    float4 b = *(const float4*)(bias + j0);
    #pragma unroll
    for (int i = 0; i < 4; ++i) {
        int node = nbase + n0 + i;
        if (node < N_NODES) {
            float4 r;
            r.x = fmaxf(acc[i][0] + b.x, 0.f);
            r.y = fmaxf(acc[i][1] + b.y, 0.f);
            r.z = fmaxf(acc[i][2] + b.z, 0.f);
            r.w = fmaxf(acc[i][3] + b.w, 0.f);
            *(float4*)(out + (size_t)node * C_FEAT + j0) = r;
        }
    }
}

// ---------------- fused adversary MLP + h1 add ----------------
// out = (relu(h2 @ Wa1 + ba1) @ Wa2 + ba2) + h1
__global__ __launch_bounds__(256) void adv_fused(const float* __restrict__ h2,
                                                 const float* __restrict__ Wa1,  // [64,128]
                                                 const float* __restrict__ ba1,  // [128]
                                                 const float* __restrict__ Wa2,  // [128,64]
                                                 const float* __restrict__ ba2,  // [64]
                                                 const float* __restrict__ h1,
                                                 float* __restrict__ out) {
    __shared__ float sH[64][68];
    __shared__ float sT[64][132];  // relu(h2@Wa1+ba1) tile, 128 wide + pad
    const int nbase = blockIdx.x * 64;
    const int tid = threadIdx.x;
    const int j0 = (tid & 15) * 4;
    const int n0 = (tid >> 4) * 4;

    // stage h2 tile
    #pragma unroll
    for (int i = 0; i < 4; ++i) {
        int row  = (tid >> 4) + i * 16;
        int col4 = (tid & 15);
        int node = nbase + row;
        float4 v = make_float4(0.f, 0.f, 0.f, 0.f);
        if (node < N_NODES)
            v = *(const float4*)(h2 + (size_t)node * C_FEAT + col4 * 4);
        *(float4*)&sH[row][col4 * 4] = v;
    }
    __syncthreads();

    // GEMM A: sT = relu(sH @ Wa1 + ba1), 128 outputs in two 64-wide halves
    #pragma unroll
    for (int half = 0; half < 2; ++half) {
        const int j = half * 64 + j0;
        float acc[4][4] = {};
        #pragma unroll 8
        for (int k = 0; k < 64; ++k) {
            float4 w = *(const float4*)(Wa1 + k * 128 + j);
            float a0 = sH[n0 + 0][k];
            float a1 = sH[n0 + 1][k];
            float a2 = sH[n0 + 2][k];
            float a3 = sH[n0 + 3][k];
            acc[0][0] = fmaf(a0, w.x, acc[0][0]); acc[0][1] = fmaf(a0, w.y, acc[0][1]);
            acc[0][2] = fmaf(a0, w.z, acc[0][2]); acc[0][3] = fmaf(a0, w.w, acc[0][3]);
            acc[1][0] = fmaf(a1, w.x, acc[1][0]); acc[1][1] = fmaf(a1, w.y, acc[1][1]);
            acc[1][2] = fmaf(a1, w.z, acc[1][2]); acc[1][3] = fmaf(a1, w.w, acc[1][3]);
            acc[2][0] = fmaf(a2, w.x, acc[2][0]); acc[2][1] = fmaf(a2, w.y, acc[2][1]);
            acc[2][2] = fmaf(a2, w.z, acc[2][2]); acc[2][3] = fmaf(a2, w.w, acc[2][3]);
            acc[3][0] = fmaf(a3, w.x, acc[3][0]); acc[3][1] = fmaf(a3, w.y, acc[3][1]);
            acc[3][2] = fmaf(a3, w.z, acc[3][2]); acc[3][3] = fmaf(a3, w.w, acc[3][3]);
        }
        float4 b1 = *(const float4*)(ba1 + j);
        #pragma unroll
        for (int i = 0; i < 4; ++i) {
            float4 r;
            r.x = fmaxf(acc[i][0] + b1.x, 0.f);
            r.y = fmaxf(acc[i][1] + b1.y, 0.f);
            r.z = fmaxf(acc[i][2] + b1.z, 0.f);
            r.w = fmaxf(acc[i][3] + b1.w, 0.f);
            *(float4*)&sT[n0 + i][j] = r;
        }
    }
    __syncthreads();

    // GEMM B: out = sT @ Wa2 + ba2 + h1
    float acc[4][4] = {};
    #pragma unroll 8
    for (int k = 0; k < 128; ++k) {
        float4 w = *(const float4*)(Wa2 + k * 64 + j0);
        float a0 = sT[n0 + 0][k];
        float a1 = sT[n0 + 1][k];
        float a2 = sT[n0 + 2][k];
        float a3 = sT[n0 + 3][k];
        acc[0][0] = fmaf(a0, w.x, acc[0][0]); acc[0][1] = fmaf(a0, w.y, acc[0][1]);
        acc[0][2] = fmaf(a0, w.z, acc[0][2]); acc[0][3] = fmaf(a0, w.w, acc[0][3]);
        acc[1][0] = fmaf(a1, w.x, acc[1][0]); acc[1][1] = fmaf(a1, w.y, acc[1][1]);
        acc[1][2] = fmaf(a1, w.z, acc[1][2]); acc[1][3] = fmaf(a1, w.w, acc[1][3]);
        acc[2][0] = fmaf(a2, w.x, acc[2][0]); acc[2][1] = fmaf(a2, w.y, acc[2][1]);
        acc[2][2] = fmaf(a2, w.z, acc[2][2]); acc[2][3] = fmaf(a2, w.w, acc[2][3]);
        acc[3][0] = fmaf(a3, w.x, acc[3][0]); acc[3][1] = fmaf(a3, w.y, acc[3][1]);
        acc[3][2] = fmaf(a3, w.z, acc[3][2]); acc[3][3] = fmaf(a3, w.w, acc[3][3]);
    }
    float4 b2 = *(const float4*)(ba2 + j0);
    #pragma unroll
    for (int i = 0; i < 4; ++i) {
        int node = nbase + n0 + i;
        if (node < N_NODES) {
            float4 h = *(const float4*)(h1 + (size_t)node * C_FEAT + j0);
            float4 r;
            r.x = acc[i][0] + b2.x + h.x;
            r.y = acc[i][1] + b2.y + h.y;
            r.z = acc[i][2] + b2.z + h.z;
            r.w = acc[i][3] + b2.w + h.w;
            *(float4*)(out + (size_t)node * C_FEAT + j0) = r;
        }
    }
}

extern "C" void kernel_launch(void* const* d_in, const int* in_sizes, int n_in,
                              void* d_out, int out_size, void* d_ws, size_t ws_size,
                              hipStream_t stream) {
    const float* x   = (const float*)d_in[0];
    const int*   ei  = (const int*)d_in[1];
    const int*   tix = (const int*)d_in[2];
    const float* Wt1 = (const float*)d_in[3];
    const float* bt1 = (const float*)d_in[4];
    const float* Wt2 = (const float*)d_in[5];
    const float* bt2 = (const float*)d_in[6];
    const float* Wa1 = (const float*)d_in[7];
    const float* ba1 = (const float*)d_in[8];
    const float* Wa2 = (const float*)d_in[9];
    const float* ba2 = (const float*)d_in[10];
    float* out = (float*)d_out;

    const int* src = ei;
    const int* dst = ei + E_EDGES;

    float* cat = (float*)d_ws;                              // [N, T*C] 102.4 MB
    float* h1  = cat + (size_t)N_NODES * K_DIM;             // [N, C]
    float* h2  = h1 + (size_t)N_NODES * C_FEAT;             // [N, C]

    const int catN   = N_NODES * K_DIM;        // 25.6M floats
    const int zBlk   = (catN / 4 + 255) / 256;
    const int sBlk   = (E_EDGES * 16 + 255) / 256;          // 50000
    const int gBlk   = (N_NODES + 63) / 64;                 // 782

    // conv1: out -> h1
    zero_f4<<<zBlk, 256, 0, stream>>>(cat, catN / 4);
    scatter_add<<<sBlk, 256, 0, stream>>>(x, src, dst, tix, cat);
    gemm_tlin<<<gBlk, 256, 0, stream>>>(cat, Wt1, bt1, h1);

    // conv2: h1 -> h2
    zero_f4<<<zBlk, 256, 0, stream>>>(cat, catN / 4);
    scatter_add<<<sBlk, 256, 0, stream>>>(h1, src, dst, tix, cat);
    gemm_tlin<<<gBlk, 256, 0, stream>>>(cat, Wt2, bt2, h2);

    // adversary MLP + h1  (out = h1 + adv; third conv == h1 reuse)
    adv_fused<<<gBlk, 256, 0, stream>>>(h2, Wa1, ba1, Wa2, ba2, h1, out);
}

// Round 2
// 601.884 us; speedup vs baseline: 2.6981x; 2.6981x over previous
//
#include <hip/hip_runtime.h>

#define N_NODES 50000
#define T_STEPS 8
#define C_FEAT  64
#define E_EDGES 800000
#define NBLK_SCAN 49   // ceil(N/1024)

// ---------------- tiny utility kernels ----------------
__global__ __launch_bounds__(256) void zero_int(int* __restrict__ p, int n) {
    int i = blockIdx.x * 256 + threadIdx.x;
    if (i < n) p[i] = 0;
}

// ---------------- CSR build: hist -> scan -> scatter ----------------
__global__ __launch_bounds__(256) void hist_dst(const int* __restrict__ dst, int* __restrict__ cnt) {
    int e = blockIdx.x * 256 + threadIdx.x;
    if (e < E_EDGES) atomicAdd(&cnt[dst[e]], 1);
}

__global__ __launch_bounds__(1024) void scan1(int* __restrict__ arr, int* __restrict__ bsum) {
    __shared__ int s[1024];
    int i = blockIdx.x * 1024 + threadIdx.x;
    int v = (i < N_NODES) ? arr[i] : 0;
    s[threadIdx.x] = v;
    __syncthreads();
    int acc = v;
    #pragma unroll
    for (int d = 1; d < 1024; d <<= 1) {
        int other = (threadIdx.x >= d) ? s[threadIdx.x - d] : 0;
        __syncthreads();
        acc += other;
        s[threadIdx.x] = acc;
        __syncthreads();
    }
    if (i < N_NODES) arr[i] = acc - v;              // exclusive (local)
    if (threadIdx.x == 1023) bsum[blockIdx.x] = acc; // block total
}

__global__ void scan2(const int* __restrict__ bsum, int* __restrict__ bofs) {
    if (threadIdx.x == 0) {
        int run = 0;
        for (int b = 0; b < NBLK_SCAN; ++b) { bofs[b] = run; run += bsum[b]; }
    }
}

__global__ __launch_bounds__(256) void scan3(int* __restrict__ arr, const int* __restrict__ bofs) {
    int i = blockIdx.x * 256 + threadIdx.x;
    if (i < N_NODES) arr[i] += bofs[i >> 10];
}

// After this, arr[d] (start) is atomically advanced to arr[d] (end) -> segment
// d spans [d?arr[d-1]:0, arr[d]).
__global__ __launch_bounds__(256) void scatter_edges(const int* __restrict__ src,
                                                     const int* __restrict__ dst,
                                                     const int* __restrict__ tix,
                                                     int* __restrict__ cursor,
                                                     int* __restrict__ elist) {
    int e = blockIdx.x * 256 + threadIdx.x;
    if (e >= E_EDGES) return;
    int d = dst[e];
    int pos = atomicAdd(&cursor[d], 1);
    elist[pos] = src[e] | (tix[e] << 16);
}

// ---------------- Q = A[N,64] @ Wblock[4t][64,64] -> [N, 256] ----------------
// block: 64 nodes x 128 cols; 256 threads, 4x8 micro-tile. A^T staged in LDS.
#define SAP 68
#define SWP 132
__global__ __launch_bounds__(256) void gemm_q(const float* __restrict__ A,
                                              const float* __restrict__ Wb,  // rows t0*64.., [256,64]
                                              float* __restrict__ Q) {
    __shared__ float sAT[64][SAP];   // [k][node]
    __shared__ float sW[64][SWP];    // [k][j-local]
    const int tid = threadIdx.x;
    const int nb = blockIdx.x * 64;
    const int cb = blockIdx.y;       // 0/1 -> local cols cb*128..

    // stage A^T: node = nb + tid>>2, k-quads (tid&3)+4i (coalesced 16B/lane)
    {
        int node = nb + (tid >> 2);
        int ln = tid >> 2;
        #pragma unroll
        for (int i = 0; i < 4; ++i) {
            int kq = (tid & 3) + i * 4;
            float4 v = make_float4(0.f, 0.f, 0.f, 0.f);
            if (node < N_NODES) v = *(const float4*)(A + (size_t)node * 64 + kq * 4);
            sAT[kq * 4 + 0][ln] = v.x;
            sAT[kq * 4 + 1][ln] = v.y;
            sAT[kq * 4 + 2][ln] = v.z;
            sAT[kq * 4 + 3][ln] = v.w;
        }
    }
    // stage W (permuted view: sW[k][tt*64+c] = Wb[(tt*64+k)*64+c], tt local 2)
    {
        int jq = tid & 31;
        int tt = cb * 2 + (jq >> 4);
        int c  = (jq & 15) * 4;
        int k0 = tid >> 5;
        #pragma unroll
        for (int i = 0; i < 8; ++i) {
            int k = k0 + i * 8;
            *(float4*)&sW[k][jq * 4] = *(const float4*)(Wb + (size_t)(tt * 64 + k) * 64 + c);
        }
    }
    __syncthreads();

    const int n0 = (tid >> 4) * 4;
    const int j0 = (tid & 15) * 8;
    float acc[4][8] = {};
    #pragma unroll 4
    for (int k = 0; k < 64; ++k) {
        float4 a  = *(const float4*)&sAT[k][n0];
        float4 w0 = *(const float4*)&sW[k][j0];
        float4 w1 = *(const float4*)&sW[k][j0 + 4];
        float av[4] = {a.x, a.y, a.z, a.w};
        float wv[8] = {w0.x, w0.y, w0.z, w0.w, w1.x, w1.y, w1.z, w1.w};
        #pragma unroll
        for (int i = 0; i < 4; ++i)
            #pragma unroll
            for (int j = 0; j < 8; ++j)
                acc[i][j] = fmaf(av[i], wv[j], acc[i][j]);
    }

    #pragma unroll
    for (int i = 0; i < 4; ++i) {
        int node = nb + n0 + i;
        if (node < N_NODES) {
            float* o = Q + (size_t)node * 256 + cb * 128 + j0;
            *(float4*)o       = make_float4(acc[i][0], acc[i][1], acc[i][2], acc[i][3]);
            *(float4*)(o + 4) = make_float4(acc[i][4], acc[i][5], acc[i][6], acc[i][7]);
        }
    }
}

// ---------------- gather-reduce: h[d] = (relu)(init + sum_{t in half} Q[src][t&3]) ----------------
// one wave per dst, lane = channel. No atomics.
__global__ __launch_bounds__(256) void conv_reduce(const float* __restrict__ Q,
                                                   const int* __restrict__ segend,
                                                   const int* __restrict__ elist,
                                                   const float* __restrict__ bias,
                                                   float* __restrict__ h,
                                                   int half, int do_relu) {
    int d = blockIdx.x * 4 + (threadIdx.x >> 6);
    int c = threadIdx.x & 63;
    if (d >= N_NODES) return;
    int s0 = d ? segend[d - 1] : 0;
    int s1 = segend[d];
    float acc = (half == 0) ? bias[c] : h[(size_t)d * 64 + c];
    for (int i = s0; i < s1; ++i) {
        int p = elist[i];                // wave-uniform broadcast load
        int t = p >> 16;
        if ((t >> 2) == half) {
            int s = p & 0xffff;
            acc += Q[(size_t)s * 256 + (t & 3) * 64 + c];
        }
    }
    h[(size_t)d * 64 + c] = do_relu ? fmaxf(acc, 0.f) : acc;
}

// ---------------- fused adversary MLP + h1 add ----------------
// out = (relu(h2 @ Wa1 + ba1) @ Wa2 + ba2) + h1
__global__ __launch_bounds__(256) void adv_fused(const float* __restrict__ h2,
                                                 const float* __restrict__ Wa1,  // [64,128]
                                                 const float* __restrict__ ba1,  // [128]
                                                 const float* __restrict__ Wa2,  // [128,64]
                                                 const float* __restrict__ ba2,  // [64]
                                                 const float* __restrict__ h1,
                                                 float* __restrict__ out) {
    __shared__ float sH[64][68];
    __shared__ float sT[64][132];
    const int nbase = blockIdx.x * 64;
    const int tid = threadIdx.x;
    const int j0 = (tid & 15) * 4;
    const int n0 = (tid >> 4) * 4;

    #pragma unroll
    for (int i = 0; i < 4; ++i) {
        int row  = (tid >> 4) + i * 16;
        int col4 = (tid & 15);
        int node = nbase + row;
        float4 v = make_float4(0.f, 0.f, 0.f, 0.f);
        if (node < N_NODES)
            v = *(const float4*)(h2 + (size_t)node * C_FEAT + col4 * 4);
        *(float4*)&sH[row][col4 * 4] = v;
    }
    __syncthreads();

    #pragma unroll
    for (int half = 0; half < 2; ++half) {
        const int j = half * 64 + j0;
        float acc[4][4] = {};
        #pragma unroll 8
        for (int k = 0; k < 64; ++k) {
            float4 w = *(const float4*)(Wa1 + k * 128 + j);
            float a0 = sH[n0 + 0][k];
            float a1 = sH[n0 + 1][k];
            float a2 = sH[n0 + 2][k];
            float a3 = sH[n0 + 3][k];
            acc[0][0] = fmaf(a0, w.x, acc[0][0]); acc[0][1] = fmaf(a0, w.y, acc[0][1]);
            acc[0][2] = fmaf(a0, w.z, acc[0][2]); acc[0][3] = fmaf(a0, w.w, acc[0][3]);
            acc[1][0] = fmaf(a1, w.x, acc[1][0]); acc[1][1] = fmaf(a1, w.y, acc[1][1]);
            acc[1][2] = fmaf(a1, w.z, acc[1][2]); acc[1][3] = fmaf(a1, w.w, acc[1][3]);
            acc[2][0] = fmaf(a2, w.x, acc[2][0]); acc[2][1] = fmaf(a2, w.y, acc[2][1]);
            acc[2][2] = fmaf(a2, w.z, acc[2][2]); acc[2][3] = fmaf(a2, w.w, acc[2][3]);
            acc[3][0] = fmaf(a3, w.x, acc[3][0]); acc[3][1] = fmaf(a3, w.y, acc[3][1]);
            acc[3][2] = fmaf(a3, w.z, acc[3][2]); acc[3][3] = fmaf(a3, w.w, acc[3][3]);
        }
        float4 b1 = *(const float4*)(ba1 + j);
        #pragma unroll
        for (int i = 0; i < 4; ++i) {
            float4 r;
            r.x = fmaxf(acc[i][0] + b1.x, 0.f);
            r.y = fmaxf(acc[i][1] + b1.y, 0.f);
            r.z = fmaxf(acc[i][2] + b1.z, 0.f);
            r.w = fmaxf(acc[i][3] + b1.w, 0.f);
            *(float4*)&sT[n0 + i][j] = r;
        }
    }
    __syncthreads();

    float acc[4][4] = {};
    #pragma unroll 8
    for (int k = 0; k < 128; ++k) {
        float4 w = *(const float4*)(Wa2 + k * 64 + j0);
        float a0 = sT[n0 + 0][k];
        float a1 = sT[n0 + 1][k];
        float a2 = sT[n0 + 2][k];
        float a3 = sT[n0 + 3][k];
        acc[0][0] = fmaf(a0, w.x, acc[0][0]); acc[0][1] = fmaf(a0, w.y, acc[0][1]);
        acc[0][2] = fmaf(a0, w.z, acc[0][2]); acc[0][3] = fmaf(a0, w.w, acc[0][3]);
        acc[1][0] = fmaf(a1, w.x, acc[1][0]); acc[1][1] = fmaf(a1, w.y, acc[1][1]);
        acc[1][2] = fmaf(a1, w.z, acc[1][2]); acc[1][3] = fmaf(a1, w.w, acc[1][3]);
        acc[2][0] = fmaf(a2, w.x, acc[2][0]); acc[2][1] = fmaf(a2, w.y, acc[2][1]);
        acc[2][2] = fmaf(a2, w.z, acc[2][2]); acc[2][3] = fmaf(a2, w.w, acc[2][3]);
        acc[3][0] = fmaf(a3, w.x, acc[3][0]); acc[3][1] = fmaf(a3, w.y, acc[3][1]);
        acc[3][2] = fmaf(a3, w.z, acc[3][2]); acc[3][3] = fmaf(a3, w.w, acc[3][3]);
    }
    float4 b2 = *(const float4*)(ba2 + j0);
    #pragma unroll
    for (int i = 0; i < 4; ++i) {
        int node = nbase + n0 + i;
        if (node < N_NODES) {
            float4 hh = *(const float4*)(h1 + (size_t)node * C_FEAT + j0);
            float4 r;
            r.x = acc[i][0] + b2.x + hh.x;
            r.y = acc[i][1] + b2.y + hh.y;
            r.z = acc[i][2] + b2.z + hh.z;
            r.w = acc[i][3] + b2.w + hh.w;
            *(float4*)(out + (size_t)node * C_FEAT + j0) = r;
        }
    }
}

extern "C" void kernel_launch(void* const* d_in, const int* in_sizes, int n_in,
                              void* d_out, int out_size, void* d_ws, size_t ws_size,
                              hipStream_t stream) {
    const float* x   = (const float*)d_in[0];
    const int*   ei  = (const int*)d_in[1];
    const int*   tix = (const int*)d_in[2];
    const float* Wt1 = (const float*)d_in[3];
    const float* bt1 = (const float*)d_in[4];
    const float* Wt2 = (const float*)d_in[5];
    const float* bt2 = (const float*)d_in[6];
    const float* Wa1 = (const float*)d_in[7];
    const float* ba1 = (const float*)d_in[8];
    const float* Wa2 = (const float*)d_in[9];
    const float* ba2 = (const float*)d_in[10];
    float* out = (float*)d_out;

    const int* src = ei;
    const int* dst = ei + E_EDGES;

    // workspace layout (~80 MB, well under the 128 MB proven in R1)
    float* Q   = (float*)d_ws;                       // [N,256] f32 = 51.2 MB
    float* h1  = Q + (size_t)N_NODES * 256;          // 12.8 MB
    float* h2  = h1 + (size_t)N_NODES * 64;          // 12.8 MB
    int*   arr = (int*)(h2 + (size_t)N_NODES * 64);  // N: cnt -> offsets -> seg-ends
    int*   bsum = arr + N_NODES;                     // 64
    int*   bofs = bsum + 64;                         // 64
    int*   elist = bofs + 64;                        // E packed (src | t<<16)

    const int eBlk = (E_EDGES + 255) / 256;          // 3125
    const int nBlk256 = (N_NODES + 255) / 256;       // 196
    const int gBlkN = (N_NODES + 63) / 64;           // 782
    const int rBlk = (N_NODES + 3) / 4;              // 12500
    dim3 gQ(gBlkN, 2);

    // ---- CSR build by dst (reused for both convs) ----
    zero_int<<<nBlk256, 256, 0, stream>>>(arr, N_NODES);
    hist_dst<<<eBlk, 256, 0, stream>>>(dst, arr);
    scan1<<<NBLK_SCAN, 1024, 0, stream>>>(arr, bsum);
    scan2<<<1, 64, 0, stream>>>(bsum, bofs);
    scan3<<<nBlk256, 256, 0, stream>>>(arr, bofs);
    scatter_edges<<<eBlk, 256, 0, stream>>>(src, dst, tix, arr, elist);

    // ---- conv1: x -> h1 (two t-halves) ----
    gemm_q<<<gQ, 256, 0, stream>>>(x, Wt1, Q);                       // t 0..3
    conv_reduce<<<rBlk, 256, 0, stream>>>(Q, arr, elist, bt1, h1, 0, 0);
    gemm_q<<<gQ, 256, 0, stream>>>(x, Wt1 + 4 * 64 * 64, Q);         // t 4..7
    conv_reduce<<<rBlk, 256, 0, stream>>>(Q, arr, elist, bt1, h1, 1, 1);

    // ---- conv2: h1 -> h2 ----
    gemm_q<<<gQ, 256, 0, stream>>>(h1, Wt2, Q);
    conv_reduce<<<rBlk, 256, 0, stream>>>(Q, arr, elist, bt2, h2, 0, 0);
    gemm_q<<<gQ, 256, 0, stream>>>(h1, Wt2 + 4 * 64 * 64, Q);
    conv_reduce<<<rBlk, 256, 0, stream>>>(Q, arr, elist, bt2, h2, 1, 1);

    // ---- adversary MLP + residual (third conv == h1) ----
    adv_fused<<<gBlkN, 256, 0, stream>>>(h2, Wa1, ba1, Wa2, ba2, h1, out);
}